// Round 4
// baseline (153.102 us; speedup 1.0000x reference)
//
#include <hip/hip_runtime.h>

// SIRD RK4, round 17: 1 producer + 3 consumer waves.
//
// R13/R14/R16 all measured 98 us (115 cyc/tstep) despite producers of 29,
// 30-equivalent, and 22 slots -> the producer was NOT the pacer. The shared
// component is the single consumer wave: 2 scattered global_store_dwordx2
// per k-iter (64 lanes x 16KB stride = 64 lines each). R15 calibrated the
// scattered-store wave-stall at ~80 cyc/store -> consumer ~115 cyc/tstep,
// exactly the measured plateau. The per-segment barrier transfers the
// consumer's pace to the block.
//
// Fix: split consumption across 3 waves (k = wave-1 mod 3 of the lagged
// segment). Each consumer does ~11 k-iters/segment (~2.5k cyc incl. scatter
// stalls) vs producer ~5.9k cyc/segment -> consumers fully hidden, stalls
// overlap across SIMDs. Producer (unchanged R16 g-free core, bit-identical)
// becomes the pacer at ~46 slots/k x 4 cyc ~= 92 cyc/tstep.
//
// State (sigma, I), sigma = c*S. D from RK4-preserved invariant:
// D = fma(-kD/c, sigma, fma(-kD, I, kD*N)).

#define N_POP 1.0e7f
#define T_PTS 2048
#define KSEG 32                  // LDS slots per segment
#define SEG_T (KSEG * 2)         // tsteps covered per segment (stride 2)
#define NSEG (T_PTS / SEG_T)     // 32 segments

// One RK4 step (h=1), 22 ops, 9-op dependent cycle. Updates SG, IV in place.
#define RK4F(SG, IV)                                                         \
    do {                                                                     \
        const float pre1 = __builtin_fmaf(nh2gm, (IV), (IV));                \
        const float m1   = (SG) * (IV);                          /* c1 */    \
        const float s2   = __builtin_fmaf(nch2, m1, (SG));                   \
        const float i2   = __builtin_fmaf(h2, m1, pre1);         /* c2 */    \
        const float pre2 = __builtin_fmaf(nh2gm, i2, (IV));                  \
        const float sip1 = __builtin_fmaf(2.0f, i2, (IV));                   \
        const float m2   = s2 * i2;                              /* c3 */    \
        const float s3   = __builtin_fmaf(nch2, m2, (SG));                   \
        const float smp1 = __builtin_fmaf(2.0f, m2, m1);                     \
        const float i3   = __builtin_fmaf(h2, m2, pre2);         /* c4 */    \
        const float pre3 = __builtin_fmaf(ngm, i3, (IV));                    \
        const float sip2 = __builtin_fmaf(2.0f, i3, sip1);                   \
        const float m3   = s3 * i3;                              /* c5 */    \
        const float s4   = __builtin_fmaf(nch, m3, (SG));                    \
        const float smp2 = __builtin_fmaf(2.0f, m3, smp1);                   \
        const float i4   = m3 + pre3;                            /* c6 */    \
        const float si   = sip2 + i4;                                        \
        const float a    = __builtin_fmaf(nwgm, si, (IV));                   \
        const float m4   = s4 * i4;                              /* c7 */    \
        const float sm   = smp2 + m4;                            /* c8 */    \
        (SG) = __builtin_fmaf(nwc, sm, (SG));                    /* c9a */   \
        (IV) = __builtin_fmaf(w, sm, a);                         /* c9b */   \
    } while (0)

__global__ __launch_bounds__(256, 1) void sird_kernel(const float* __restrict__ alpha,
                                                      float* __restrict__ out) {
    const int lane = threadIdx.x & 63;
    const int wave = threadIdx.x >> 6;        // 0 = producer, 1..3 = consumers
    const int s = blockIdx.x * 64 + lane;     // scenario (same for all waves)

    // SoA, double-buffered: [buf][var][slot][lane], var 0=sigma 1=I. 32 KiB.
    __shared__ float buf[2][2][KSEG][64];

    const float beta  = alpha[s * 3 + 0];
    const float gamma = alpha[s * 3 + 1];
    const float mu    = alpha[s * 3 + 2];

    const float c     = beta * (1.0f / N_POP);
    const float gm    = gamma + mu;
    const float ngm   = -gm;
    const float h2    = 0.5f;                 // h/2, h = 1
    const float nch2  = -0.5f * c;            // -c*h/2
    const float nch   = -c;                   // -c*h
    const float nh2gm = -0.5f * gm;           // -gm*h/2
    const float w     = 1.0f / 6.0f;
    const float nwc   = -c * (1.0f / 6.0f);
    const float nwgm  = -gm * (1.0f / 6.0f);
    const float kD    = mu / gm;              // gamma,mu > 0 a.s.
    const float kDN   = kD * (float)N_POP;
    const float nkc   = -kD / c;
    const float nk    = -kD;

    float sg = c * (N_POP - 1.0f);            // sigma = c*S
    float I  = 1.0f;

    float2* __restrict__ orow = (float2*)out + (size_t)s * T_PTS;

    for (int seg = 0; seg <= NSEG; ++seg) {
        if (wave == 0) {
            if (seg < NSEG) {
                float* bsg = &buf[seg & 1][0][0][lane];
                float* bI  = &buf[seg & 1][1][0][lane];
#pragma unroll
                for (int k = 0; k < KSEG; ++k) {
                    bsg[k * 64] = sg;          // ds_write_b32, immediate offset
                    bI [k * 64] = I;
                    RK4F(sg, I);               // even -> odd
                    RK4F(sg, I);               // odd  -> next even
                }
            }
        } else {
            if (seg >= 1) {
                const float* qsg = &buf[(seg - 1) & 1][0][0][lane];
                const float* qI  = &buf[(seg - 1) & 1][1][0][lane];
                float2* op = orow + (size_t)(seg - 1) * SEG_T;
                // Waves 1..3 each take every 3rd k-slot; scatter stalls
                // overlap across SIMDs and each wave has ~2.3x slack.
                for (int k = wave - 1; k < KSEG; k += 3) {
                    float sgv = qsg[k * 64];
                    float Iv  = qI [k * 64];
                    const float D0 = __builtin_fmaf(nkc, sgv,
                                     __builtin_fmaf(nk, Iv, kDN));
                    op[2 * k] = make_float2(Iv, D0);
                    RK4F(sgv, Iv);             // identical recompute of odd t
                    const float D1 = __builtin_fmaf(nkc, sgv,
                                     __builtin_fmaf(nk, Iv, kDN));
                    op[2 * k + 1] = make_float2(Iv, D1);
                }
            }
        }
        __syncthreads();
    }
}

extern "C" void kernel_launch(void* const* d_in, const int* in_sizes, int n_in,
                              void* d_out, int out_size, void* d_ws, size_t ws_size,
                              hipStream_t stream) {
    const float* alpha = (const float*)d_in[0];
    float* out = (float*)d_out;
    sird_kernel<<<dim3(T_PTS / 64), dim3(256), 0, stream>>>(alpha, out);
}

// Round 5
// 148.131 us; speedup vs baseline: 1.0336x; 1.0336x over previous
//
#include <hip/hip_runtime.h>

// SIRD RK4, round 18: barrier-free producer/consumer via LDS mailbox flags.
//
// R13/R14/R16/R17 all = 98.0 us (115 cyc/tstep) despite varying producer
// slots (29/15pk/22), chain (12/13/9) and consumer split (1 or 3 waves).
// The invariant: __syncthreads per segment emits s_waitcnt vmcnt(0) before
// s_barrier, so every segment the block waits for ALL scattered global
// stores (64 x 16KB-stride lines per store) to fully drain. That ~1.4k
// cyc/segment (~23 cyc/tstep) surcharge is what every variant shared.
//
// This round: no __syncthreads in the loop. LDS flags handshake:
//   producer: wait cons_flag[b][*] >= seg-2 (acquire), fill buffer b,
//             prod_flag[b] = seg (release -> lgkmcnt drain only).
//   consumer: wait prod_flag[b] >= seg (acquire), ds_read, compute, store
//             (fire-and-forget, vmcnt NEVER drained in-loop),
//             cons_flag[b][w] = seg (relaxed; ds_read data already in regs
//             by data dependence).
// Producer pace: 46 slots/k-iter x 4 cyc ~= 92 cyc/tstep.
//
// Math/stores bit-identical to R16/R17 (same RK4F g-free core, same
// D-invariant: D = fma(-kD/c, sigma, fma(-kD, I, kD*N))).

#define N_POP 1.0e7f
#define T_PTS 2048
#define KSEG 32                  // LDS slots per segment
#define SEG_T (KSEG * 2)         // tsteps covered per segment (stride 2)
#define NSEG (T_PTS / SEG_T)     // 32 segments

#define LOAD_ACQ(p)  __hip_atomic_load((p), __ATOMIC_ACQUIRE, __HIP_MEMORY_SCOPE_WORKGROUP)
#define STORE_REL(p, v) __hip_atomic_store((p), (v), __ATOMIC_RELEASE, __HIP_MEMORY_SCOPE_WORKGROUP)
#define STORE_RLX(p, v) __hip_atomic_store((p), (v), __ATOMIC_RELAXED, __HIP_MEMORY_SCOPE_WORKGROUP)

// One RK4 step (h=1), 22 ops, 9-op dependent cycle. Updates SG, IV in place.
#define RK4F(SG, IV)                                                         \
    do {                                                                     \
        const float pre1 = __builtin_fmaf(nh2gm, (IV), (IV));                \
        const float m1   = (SG) * (IV);                          /* c1 */    \
        const float s2   = __builtin_fmaf(nch2, m1, (SG));                   \
        const float i2   = __builtin_fmaf(h2, m1, pre1);         /* c2 */    \
        const float pre2 = __builtin_fmaf(nh2gm, i2, (IV));                  \
        const float sip1 = __builtin_fmaf(2.0f, i2, (IV));                   \
        const float m2   = s2 * i2;                              /* c3 */    \
        const float s3   = __builtin_fmaf(nch2, m2, (SG));                   \
        const float smp1 = __builtin_fmaf(2.0f, m2, m1);                     \
        const float i3   = __builtin_fmaf(h2, m2, pre2);         /* c4 */    \
        const float pre3 = __builtin_fmaf(ngm, i3, (IV));                    \
        const float sip2 = __builtin_fmaf(2.0f, i3, sip1);                   \
        const float m3   = s3 * i3;                              /* c5 */    \
        const float s4   = __builtin_fmaf(nch, m3, (SG));                    \
        const float smp2 = __builtin_fmaf(2.0f, m3, smp1);                   \
        const float i4   = m3 + pre3;                            /* c6 */    \
        const float si   = sip2 + i4;                                        \
        const float a    = __builtin_fmaf(nwgm, si, (IV));                   \
        const float m4   = s4 * i4;                              /* c7 */    \
        const float sm   = smp2 + m4;                            /* c8 */    \
        (SG) = __builtin_fmaf(nwc, sm, (SG));                    /* c9a */   \
        (IV) = __builtin_fmaf(w, sm, a);                         /* c9b */   \
    } while (0)

__global__ __launch_bounds__(256, 1) void sird_kernel(const float* __restrict__ alpha,
                                                      float* __restrict__ out) {
    const int lane = threadIdx.x & 63;
    const int wave = threadIdx.x >> 6;        // 0 = producer, 1..3 = consumers
    const int s = blockIdx.x * 64 + lane;     // scenario (same for all waves)

    // SoA, double-buffered: [buf][var][slot][lane], var 0=sigma 1=I. 32 KiB.
    __shared__ float buf[2][2][KSEG][64];
    __shared__ int prod_flag[2];              // last seg written into buffer b
    __shared__ int cons_flag[2][3];           // last seg consumed, per wave

    if (threadIdx.x == 0) {
        prod_flag[0] = prod_flag[1] = -1;
        cons_flag[0][0] = cons_flag[0][1] = cons_flag[0][2] = -1;
        cons_flag[1][0] = cons_flag[1][1] = cons_flag[1][2] = -1;
    }
    __syncthreads();                          // once, before any global store

    const float beta  = alpha[s * 3 + 0];
    const float gamma = alpha[s * 3 + 1];
    const float mu    = alpha[s * 3 + 2];

    const float c     = beta * (1.0f / N_POP);
    const float gm    = gamma + mu;
    const float ngm   = -gm;
    const float h2    = 0.5f;                 // h/2, h = 1
    const float nch2  = -0.5f * c;            // -c*h/2
    const float nch   = -c;                   // -c*h
    const float nh2gm = -0.5f * gm;           // -gm*h/2
    const float w     = 1.0f / 6.0f;
    const float nwc   = -c * (1.0f / 6.0f);
    const float nwgm  = -gm * (1.0f / 6.0f);
    const float kD    = mu / gm;              // gamma,mu > 0 a.s.
    const float kDN   = kD * (float)N_POP;
    const float nkc   = -kD / c;
    const float nk    = -kD;

    float sg = c * (N_POP - 1.0f);            // sigma = c*S
    float I  = 1.0f;

    float2* __restrict__ orow = (float2*)out + (size_t)s * T_PTS;

    if (wave == 0) {
        // ------------------------------ producer ------------------------------
        for (int seg = 0; seg < NSEG; ++seg) {
            const int b = seg & 1;
            if (seg >= 2) {
                // Buffer b was last read by consumers at segment seg-2.
                while (LOAD_ACQ(&cons_flag[b][0]) < seg - 2 ||
                       LOAD_ACQ(&cons_flag[b][1]) < seg - 2 ||
                       LOAD_ACQ(&cons_flag[b][2]) < seg - 2) { /* spin */ }
            }
            float* bsg = &buf[b][0][0][lane];
            float* bI  = &buf[b][1][0][lane];
#pragma unroll
            for (int k = 0; k < KSEG; ++k) {
                bsg[k * 64] = sg;              // ds_write_b32, immediate offset
                bI [k * 64] = I;
                RK4F(sg, I);                   // even -> odd
                RK4F(sg, I);                   // odd  -> next even
            }
            if (lane == 0) STORE_REL(&prod_flag[b], seg);  // lgkmcnt drain only
        }
    } else {
        // ------------------------------ consumers -----------------------------
        const int wv = wave - 1;              // 0..2
        for (int seg = 0; seg < NSEG; ++seg) {
            const int b = seg & 1;
            while (LOAD_ACQ(&prod_flag[b]) < seg) { /* spin */ }
            const float* qsg = &buf[b][0][0][lane];
            const float* qI  = &buf[b][1][0][lane];
            float2* op = orow + (size_t)seg * SEG_T;
            for (int k = wv; k < KSEG; k += 3) {
                float sgv = qsg[k * 64];
                float Iv  = qI [k * 64];
                const float D0 = __builtin_fmaf(nkc, sgv,
                                 __builtin_fmaf(nk, Iv, kDN));
                op[2 * k] = make_float2(Iv, D0);      // fire-and-forget
                RK4F(sgv, Iv);                 // identical recompute of odd t
                const float D1 = __builtin_fmaf(nkc, sgv,
                                 __builtin_fmaf(nk, Iv, kDN));
                op[2 * k + 1] = make_float2(Iv, D1);  // fire-and-forget
            }
            // ds_read data already consumed (in registers) -> relaxed is safe;
            // crucially does NOT wait on the global stores (no vmcnt drain).
            if (lane == 0) STORE_RLX(&cons_flag[b][wv], seg);
        }
    }
}

extern "C" void kernel_launch(void* const* d_in, const int* in_sizes, int n_in,
                              void* d_out, int out_size, void* d_ws, size_t ws_size,
                              hipStream_t stream) {
    const float* alpha = (const float*)d_in[0];
    float* out = (float*)d_out;
    sird_kernel<<<dim3(T_PTS / 64), dim3(256), 0, stream>>>(alpha, out);
}